// Round 1
// baseline (1156.594 us; speedup 1.0000x reference)
//
#include <hip/hip_runtime.h>
#include <hip/hip_bf16.h>

// Bahdanau additive attention, B=64, S=2048, H=1024 (fp32 in/out).
//   score[b,s] = sum_o v[o] * tanh( (enc[b,s,:].W_h[o,:]) + dp[b,o] )
//   weights = softmax_s(score);  context[b,:] = sum_s weights[b,s]*enc[b,s,:]
//
// R3: pre-convert enc fp32->bf16 (one 768MB pass) so the score GEMM stages
// BOTH A and B tiles via async 16B global_load_lds with XOR chunk swizzle
// (pure m97 structure, ~900 TF proven) instead of reg-staging+packing A every
// K-step (~550 TF). Fallback to in-kernel conversion if workspace too small.
//
// d_ws: [0,256KB) dec_proj fp32 [64][1024]; [256KB,2.25MB) W_h bf16;
//       [2.25MB, +256MB) enc bf16 (optional, guarded by ws_size).

#define B_ 64
#define S_ 2048
#define H_ 1024

typedef __attribute__((ext_vector_type(8))) short short8;   // 8 bf16
typedef __attribute__((ext_vector_type(4))) float floatx4;  // MFMA acc

__device__ __forceinline__ short f2bf(float f) {
    unsigned u = __float_as_uint(f);
    return (short)((u + 0x7FFFu + ((u >> 16) & 1u)) >> 16);  // RTNE
}
__device__ __forceinline__ unsigned pk2bf(float a, float b) {  // low=a, high=b
    unsigned ua = __float_as_uint(a), ub = __float_as_uint(b);
    ua = (ua + 0x7FFFu + ((ua >> 16) & 1u)) >> 16;
    ub = (ub + 0x7FFFu + ((ub >> 16) & 1u)) & 0xFFFF0000u;
    return ua | ub;
}
__device__ __forceinline__ void gload_lds16(const void* g, void* l) {
    __builtin_amdgcn_global_load_lds(
        (const __attribute__((address_space(1))) unsigned*)g,
        (__attribute__((address_space(3))) unsigned*)l, 16, 0, 0);
}

// ---------------- zero the score region (atomicAdd target) ----------------
__global__ __launch_bounds__(256) void zero_score_kernel(float* __restrict__ sc) {
    ((float4*)sc)[blockIdx.x * 256 + threadIdx.x] = make_float4(0.f, 0.f, 0.f, 0.f);
}

// ---------------- dec_proj[b,o] = sum_h dec[b,h] * W_s[o,h] ----------------
__global__ __launch_bounds__(256) void dec_proj_kernel(
        const float* __restrict__ dec, const float* __restrict__ Ws,
        float* __restrict__ dp) {
    __shared__ float sdec[H_];
    const int b = blockIdx.y;
    const int o = blockIdx.x * 256 + threadIdx.x;
    ((float4*)sdec)[threadIdx.x] = ((const float4*)(dec + b * H_))[threadIdx.x];
    __syncthreads();
    const float4* wr = (const float4*)(Ws + (size_t)o * H_);
    float acc = 0.f;
#pragma unroll 4
    for (int i = 0; i < H_ / 4; ++i) {
        float4 wv = wr[i];
        acc += sdec[4*i+0]*wv.x + sdec[4*i+1]*wv.y + sdec[4*i+2]*wv.z + sdec[4*i+3]*wv.w;
    }
    dp[b * H_ + o] = acc;
}

// ---------------- W_h fp32 -> bf16 ----------------
__global__ __launch_bounds__(256) void cvt_wh_kernel(
        const float* __restrict__ Wh, short* __restrict__ Wbf) {
    const int i = blockIdx.x * 256 + threadIdx.x;
    float4 f = ((const float4*)Wh)[i];
    *(short4*)&Wbf[i * 4] = make_short4(f2bf(f.x), f2bf(f.y), f2bf(f.z), f2bf(f.w));
}

// ---------------- enc fp32 -> bf16 (grid-stride, 32B/thread/iter) ----------------
__global__ __launch_bounds__(256) void cvt_enc_kernel(
        const float* __restrict__ enc, short* __restrict__ out) {
    const size_t total = (size_t)B_ * S_ * H_ / 8;   // 16.78M 8-float chunks
    for (size_t c = (size_t)blockIdx.x * 256 + threadIdx.x; c < total;
         c += (size_t)gridDim.x * 256) {
        const float4* p = (const float4*)enc + c * 2;
        float4 f0 = p[0], f1 = p[1];
        union { short8 s; unsigned u[4]; } cv;
        cv.u[0] = pk2bf(f0.x, f0.y);
        cv.u[1] = pk2bf(f0.z, f0.w);
        cv.u[2] = pk2bf(f1.x, f1.y);
        cv.u[3] = pk2bf(f1.z, f1.w);
        ((short8*)out)[c] = cv.s;
    }
}

// ---------------- fused score GEMM ----------------
// grid.x = (M/128)*(N/128) = 1024*8; mtile = bid>>3, nb = bid&7 (nb-siblings
// adjacent -> concurrent A-tile reads hit L3; nb<->XCD keeps W slice in L2).
// USE_BF=1: A staged via global_load_lds from pre-converted bf16 enc.
// USE_BF=0: A reg-staged fp32->bf16 (fallback), same swizzled LDS layout.
template<int USE_BF>
__global__ __launch_bounds__(256, 3) void score_kernel(
        const float* __restrict__ enc, const short* __restrict__ encbf,
        const short* __restrict__ Wbf, const float* __restrict__ dp,
        const float* __restrict__ v, float* __restrict__ score) {
    __shared__ short As[128 * 64];    // 16384 B, As[m][c8] holds global chunk c8^(m&7)
    __shared__ short Bs[128 * 64];    // 16384 B, Bs[n][c8] holds global chunk c8^(n&7)

    const int tid  = threadIdx.x;
    const int wave = tid >> 6;
    const int lane = tid & 63;
    const int l15  = lane & 15;
    const int quad = lane >> 4;
    const int wy   = wave & 1;        // m-half
    const int wx   = wave >> 1;       // n-half

    const int mtile = blockIdx.x >> 3;
    const int nb    = blockIdx.x & 7;
    const int m0    = mtile * 128;    // global row index (b*S + s)
    const int n0    = nb * 128;
    const int b     = m0 >> 11;       // 16 M-tiles per batch

    floatx4 acc[4][4];
#pragma unroll
    for (int i = 0; i < 4; ++i)
#pragma unroll
        for (int j = 0; j < 4; ++j) acc[i][j] = (floatx4){0.f, 0.f, 0.f, 0.f};

    // frag read bases (row-major [128][64] bf16, XOR-chunk swizzled)
    const short* aLds = As + (wy * 64 + l15) * 64;   // + i*16*64 + swz-chunk*8
    const short* bLds = Bs + (wx * 64 + l15) * 64;   // + j*16*64 + swz-chunk*8
    const int swz = l15 & 7;

    const int srow = tid >> 3;        // staging: row-within-32 per round
    const int bc   = tid & 7;         // chunk id within row

    for (int k0 = 0; k0 < H_; k0 += 64) {
        // ---- B tile: 128 rows x 64 k bf16 via async 16B direct-to-LDS ----
#pragma unroll
        for (int r = 0; r < 4; ++r) {
            const int n = r * 32 + srow;
            const int g = bc ^ (n & 7);                // XOR chunk swizzle (global side)
            const short* gp = Wbf + (size_t)(n0 + n) * H_ + k0 + g * 8;
            gload_lds16(gp, (void*)(Bs + (r * 256 + wave * 64) * 8));
        }
        // ---- A tile ----
        if (USE_BF) {
#pragma unroll
            for (int r = 0; r < 4; ++r) {
                const int m = r * 32 + srow;
                const int g = bc ^ (m & 7);
                const short* gp = encbf + (size_t)(m0 + m) * H_ + k0 + g * 8;
                gload_lds16(gp, (void*)(As + (r * 256 + wave * 64) * 8));
            }
        } else {
#pragma unroll
            for (int i = 0; i < 4; ++i) {
                const int La = i * 256 + tid;          // 8-float chunk id
                const int m  = La >> 3;
                const int c8 = La & 7;
                const float4* gp = (const float4*)(enc + (size_t)(m0 + m) * H_ + k0 + c8 * 8);
                float4 f0 = gp[0], f1 = gp[1];
                union { short8 s; unsigned u[4]; } cv;
                cv.u[0] = pk2bf(f0.x, f0.y);
                cv.u[1] = pk2bf(f0.z, f0.w);
                cv.u[2] = pk2bf(f1.x, f1.y);
                cv.u[3] = pk2bf(f1.z, f1.w);
                *(short8*)&As[m * 64 + (c8 ^ (m & 7)) * 8] = cv.s;  // swizzled write
            }
        }
        __syncthreads();   // drains vmcnt (async A/B) + lgkm (fallback A writes)

        // ---- compute: 2 kt x (4 a-frag + 4 b-frag reads, 16 MFMA) ----
#pragma unroll
        for (int kt = 0; kt < 2; ++kt) {
            short8 af[4], bfr[4];
#pragma unroll
            for (int i = 0; i < 4; ++i)
                af[i] = *(const short8*)(aLds + i * 16 * 64 + (((kt * 4 + quad) ^ swz) * 8));
#pragma unroll
            for (int j = 0; j < 4; ++j)
                bfr[j] = *(const short8*)(bLds + j * 16 * 64 + (((kt * 4 + quad) ^ swz) * 8));
#pragma unroll
            for (int i = 0; i < 4; ++i)
#pragma unroll
                for (int j = 0; j < 4; ++j)
                    acc[i][j] = __builtin_amdgcn_mfma_f32_16x16x32_bf16(af[i], bfr[j], acc[i][j], 0, 0, 0);
        }
        __syncthreads();   // protect LDS before next stage
    }

    // ---- fused epilogue: +dp, tanh, *v, reduce over block's 128 cols ----
    float part[4][4];
#pragma unroll
    for (int i = 0; i < 4; ++i)
#pragma unroll
        for (int r = 0; r < 4; ++r) part[i][r] = 0.f;

#pragma unroll
    for (int j = 0; j < 4; ++j) {
        const int o = n0 + wx * 64 + j * 16 + l15;
        const float dpv = dp[b * H_ + o];
        const float vv  = v[o];
#pragma unroll
        for (int i = 0; i < 4; ++i)
#pragma unroll
            for (int r = 0; r < 4; ++r) {
                float x = acc[i][j][r] + dpv;          // D[row=quad*4+r][col=l15]
                x = fminf(10.f, fmaxf(-10.f, x));
                float e = __expf(x + x);               // e^(2x)
                float t = 1.f - 2.f * __builtin_amdgcn_rcpf(e + 1.f);
                part[i][r] += t * vv;
            }
    }
#pragma unroll
    for (int i = 0; i < 4; ++i)
#pragma unroll
        for (int r = 0; r < 4; ++r) {
            float s = part[i][r];
            s += __shfl_xor(s, 1, 64);
            s += __shfl_xor(s, 2, 64);
            s += __shfl_xor(s, 4, 64);
            s += __shfl_xor(s, 8, 64);
            if (l15 == 0)   // 4 lanes (quad) hold rows quad*4+r of frag i
                atomicAdd(&score[m0 + wy * 64 + i * 16 + quad * 4 + r], s);
        }
}

// ---------------- softmax over S in-place + zero context ----------------
__global__ __launch_bounds__(256) void softmax_kernel(float* __restrict__ out) {
    const int b = blockIdx.x;
    const int tid = threadIdx.x;
    float* sc = out + B_ * H_ + b * S_;

    ((float4*)(out + b * H_))[tid] = make_float4(0.f, 0.f, 0.f, 0.f);

    float xs[8];
    float m = -1e30f;
#pragma unroll
    for (int i = 0; i < 8; ++i) { xs[i] = sc[tid + i * 256]; m = fmaxf(m, xs[i]); }
#pragma unroll
    for (int off = 32; off > 0; off >>= 1) m = fmaxf(m, __shfl_xor(m, off, 64));
    __shared__ float redm[4];
    const int wv = tid >> 6;
    if ((tid & 63) == 0) redm[wv] = m;
    __syncthreads();
    m = fmaxf(fmaxf(redm[0], redm[1]), fmaxf(redm[2], redm[3]));

    float s = 0.f;
#pragma unroll
    for (int i = 0; i < 8; ++i) { xs[i] = __expf(xs[i] - m); s += xs[i]; }
#pragma unroll
    for (int off = 32; off > 0; off >>= 1) s += __shfl_xor(s, off, 64);
    __shared__ float reds[4];
    if ((tid & 63) == 0) reds[wv] = s;
    __syncthreads();
    s = reds[0] + reds[1] + reds[2] + reds[3];

    const float inv = 1.f / s;
#pragma unroll
    for (int i = 0; i < 8; ++i) sc[tid + i * 256] = xs[i] * inv;
}

// ---------------- context[b,h] = sum_s weights[b,s] * enc[b,s,h] ----------------
__global__ __launch_bounds__(256) void context_kernel(
        const float* __restrict__ enc, const float* __restrict__ wts,
        float* __restrict__ ctx) {
    const int b    = blockIdx.x;
    const int scnk = blockIdx.y;
    const int t    = threadIdx.x;
    const float* w  = wts + b * S_ + scnk * 256;
    const float4* e = (const float4*)(enc + ((long)b * S_ + scnk * 256) * H_);
    float4 acc = make_float4(0.f, 0.f, 0.f, 0.f);
#pragma unroll 4
    for (int s = 0; s < 256; ++s) {
        const float ww = w[s];
        const float4 ev = e[s * (H_ / 4) + t];
        acc.x = fmaf(ww, ev.x, acc.x);
        acc.y = fmaf(ww, ev.y, acc.y);
        acc.z = fmaf(ww, ev.z, acc.z);
        acc.w = fmaf(ww, ev.w, acc.w);
    }
    float* c = ctx + b * H_ + t * 4;
    atomicAdd(c + 0, acc.x);
    atomicAdd(c + 1, acc.y);
    atomicAdd(c + 2, acc.z);
    atomicAdd(c + 3, acc.w);
}

extern "C" void kernel_launch(void* const* d_in, const int* in_sizes, int n_in,
                              void* d_out, int out_size, void* d_ws, size_t ws_size,
                              hipStream_t stream) {
    const float* dec = (const float*)d_in[0];   // [64,1,1024]
    const float* enc = (const float*)d_in[1];   // [64,2048,1024]
    const float* Wh  = (const float*)d_in[2];   // [1024,1024]
    const float* Ws  = (const float*)d_in[3];   // [1024,1024]
    const float* v   = (const float*)d_in[4];   // [1024]

    float* out = (float*)d_out;
    float* ctx = out;                 // [64*1024] context
    float* wts = out + B_ * H_;       // [64*2048] scores -> weights (in place)

    float* dp  = (float*)d_ws;                                      // 256 KB
    short* Wbf = (short*)((char*)d_ws + (size_t)B_ * H_ * 4);       // 2 MB bf16
    const size_t base = (size_t)B_ * H_ * 4 + (size_t)H_ * H_ * 2;  // 2.25 MB
    const size_t enc_need = (size_t)B_ * S_ * H_ * 2;               // 256 MB
    short* encbf = (ws_size >= base + enc_need)
                       ? (short*)((char*)d_ws + base) : nullptr;
    (void)in_sizes; (void)n_in; (void)out_size;

    zero_score_kernel<<<(B_ * S_ / 4) / 256, 256, 0, stream>>>(wts);
    dec_proj_kernel<<<dim3(H_ / 256, B_), 256, 0, stream>>>(dec, Ws, dp);
    cvt_wh_kernel<<<(H_ * H_ / 4) / 256, 256, 0, stream>>>(Wh, Wbf);
    if (encbf) {
        cvt_enc_kernel<<<8192, 256, 0, stream>>>(enc, encbf);
        score_kernel<1><<<(B_ * S_ / 128) * (H_ / 128), 256, 0, stream>>>(
            enc, encbf, Wbf, dp, v, wts);
    } else {
        score_kernel<0><<<(B_ * S_ / 128) * (H_ / 128), 256, 0, stream>>>(
            enc, nullptr, Wbf, dp, v, wts);
    }
    softmax_kernel<<<B_, 256, 0, stream>>>(out);
    context_kernel<<<dim3(B_, S_ / 256), 256, 0, stream>>>(enc, wts, ctx);
}